// Round 15
// baseline (253.872 us; speedup 1.0000x reference)
//
#include <hip/hip_runtime.h>
#include <cstdint>
#include <cstddef>

#define DEV __device__ __forceinline__

typedef __attribute__((ext_vector_type(8))) short bf16x8;    // 8 bf16 = 4 VGPRs
typedef __attribute__((ext_vector_type(4))) float f32x4;
typedef __attribute__((ext_vector_type(16))) float f32x16;

static_assert(sizeof(bf16x8) == 16, "frag size");

static constexpr int Bb = 2, Tt = 2048, Dd = 1024, Hh = 16, DHc = 64;
static constexpr int BT = Bb * Tt;  // 4096

DEV unsigned short f2bf(float f) {
  union { float f; unsigned u; } v; v.f = f;
  unsigned r = v.u + 0x7fffu + ((v.u >> 16) & 1u);  // RNE
  return (unsigned short)(r >> 16);
}
DEV float bf2f(unsigned short u) {
  union { unsigned u; float f; } v; v.u = (unsigned)u << 16;
  return v.f;
}

DEV void gload16(const void* g, void* l) {
  __builtin_amdgcn_global_load_lds((__attribute__((address_space(1))) void*)(g),
                                   (__attribute__((address_space(3))) void*)(l),
                                   16, 0, 0);
}

DEV f32x4 mfma16(bf16x8 a, bf16x8 b, f32x4 c) {
  return __builtin_amdgcn_mfma_f32_16x16x32_bf16(a, b, c, 0, 0, 0);
}
DEV f32x16 mfma32(bf16x8 a, bf16x8 b, f32x16 c) {
  return __builtin_amdgcn_mfma_f32_32x32x16_bf16(a, b, c, 0, 0, 0);
}

DEV unsigned cvtpk(float lo, float hi) {
  unsigned r;
  asm("v_cvt_pk_bf16_f32 %0, %1, %2" : "=v"(r) : "v"(lo), "v"(hi));
  return r;
}
DEV void plswap(unsigned& x, unsigned& y) {
  asm volatile("v_permlane32_swap_b32 %0, %1" : "+v"(x), "+v"(y));
}
DEV float exp2g(float x) {
#if __has_builtin(__builtin_amdgcn_exp2f)
  return __builtin_amdgcn_exp2f(x);
#else
  return exp2f(x);
#endif
}

// ---------------------------------------------------------------- prep
// z<6: transpose W[z] -> bf16 W^T slab; z==6: convert x -> bf16
__global__ __launch_bounds__(256) void k_prep(
    const float* __restrict__ x, const float* __restrict__ W0,
    const float* __restrict__ W1, const float* __restrict__ W2,
    const float* __restrict__ W3, const float* __restrict__ W4,
    const float* __restrict__ W5, unsigned short* __restrict__ wtsBase,
    unsigned short* __restrict__ x16) {
  const int z = blockIdx.z;
  const int tx = threadIdx.x, ty = threadIdx.y;  // block (32,8)
  if (z == 6) {
    const int flat = blockIdx.y * 32 + blockIdx.x;
    const int tid = ty * 32 + tx;
    const float4* x4 = (const float4*)x;
    ushort4* o4 = (ushort4*)x16;
#pragma unroll
    for (int u = 0; u < 4; ++u) {
      const int i = flat * 1024 + u * 256 + tid;
      float4 v = x4[i];
      ushort4 o;
      o.x = f2bf(v.x); o.y = f2bf(v.y); o.z = f2bf(v.z); o.w = f2bf(v.w);
      o4[i] = o;
    }
    return;
  }
  __shared__ float t[32][33];
  const float* W = z == 0 ? W0 : z == 1 ? W1 : z == 2 ? W2 : z == 3 ? W3 : z == 4 ? W4 : W5;
  unsigned short* Wt = wtsBase + (size_t)z * Dd * Dd;
  const int n0 = blockIdx.x * 32, k0 = blockIdx.y * 32;
#pragma unroll
  for (int i = 0; i < 4; ++i)
    t[ty + 8 * i][tx] = W[(size_t)(k0 + ty + 8 * i) * Dd + n0 + tx];
  __syncthreads();
#pragma unroll
  for (int i = 0; i < 4; ++i)
    Wt[(size_t)(n0 + ty + 8 * i) * Dd + k0 + tx] = f2bf(t[tx][ty + 8 * i]);
}

// ---------------------------------------------------------------- fused QKV GEMM
// C[4096,3072] = x16 @ Wqkv^T + bias; 128x128 tile, BK=32, 4 waves,
// 768 blocks (3/CU), 1D grid with bijective XCD swizzle (chunk=96).
// 3-deep rotating LDS buffers, counted vmcnt, one barrier per K-step.
__global__ __launch_bounds__(256, 3) void k_gemm_qkv(
    const unsigned short* __restrict__ A, const unsigned short* __restrict__ Bt,
    const float* __restrict__ bq, const float* __restrict__ bk,
    const float* __restrict__ bv, unsigned short* __restrict__ Qo,
    unsigned short* __restrict__ Ko, unsigned short* __restrict__ Vo) {
  constexpr int K = Dd;
  constexpr int NT = K / 32;  // 32
  __shared__ unsigned short sA[3][128 * 32];
  __shared__ unsigned short sB[3][128 * 32];
  const int tid = threadIdx.x;
  const int w = tid >> 6, l = tid & 63;
  const int wr = w >> 1, wc = w & 1;
  // XCD swizzle: 768 blocks, 8 XCDs -> 96 logical ids per XCD (4 rows x 24 cols)
  const int pid = blockIdx.x;
  const int logical = (pid & 7) * 96 + (pid >> 3);
  const int m0 = (logical / 24) * 128, n0 = (logical % 24) * 128;

  const f32x4 fz = {0.f, 0.f, 0.f, 0.f};
  f32x4 acc[4][4];
#pragma unroll
  for (int m = 0; m < 4; ++m)
#pragma unroll
    for (int n = 0; n < 4; ++n) acc[m][n] = fz;

  const int srow = l >> 2, scol = (l & 3) * 8;
  const unsigned short* pa = A + (size_t)(m0 + w * 32 + srow) * K + scol;
  const unsigned short* pb = Bt + (size_t)(n0 + w * 32 + srow) * K + scol;
  const int fr = l & 15, fk = (l >> 4) * 8;
  const int ar0 = (wr * 64 + fr) * 32 + fk;
  const int br0 = (wc * 64 + fr) * 32 + fk;

#define QSTAGE(tt, bb)                                            \
  do {                                                            \
    unsigned short* la = &sA[bb][(w * 32) * 32];                  \
    unsigned short* lb = &sB[bb][(w * 32) * 32];                  \
    gload16(pa + (tt) * 32, la);                                  \
    gload16(pa + (tt) * 32 + (size_t)16 * K, la + 16 * 32);       \
    gload16(pb + (tt) * 32, lb);                                  \
    gload16(pb + (tt) * 32 + (size_t)16 * K, lb + 16 * 32);       \
  } while (0)

  QSTAGE(0, 0);
  QSTAGE(1, 1);
  int bcur = 0;

  for (int t = 0; t < NT; ++t) {
    if (t < NT - 1) {
      asm volatile("s_waitcnt vmcnt(4)" ::: "memory");
    } else {
      asm volatile("s_waitcnt vmcnt(0)" ::: "memory");
    }
    __builtin_amdgcn_s_barrier();
    __builtin_amdgcn_sched_barrier(0);
    if (t + 2 < NT) {
      const int b2 = (bcur + 2 >= 3) ? bcur - 1 : bcur + 2;
      QSTAGE(t + 2, b2);
    }
    bf16x8 af[4], bg[4];
#pragma unroll
    for (int m = 0; m < 4; ++m) af[m] = *(const bf16x8*)&sA[bcur][ar0 + m * 16 * 32];
#pragma unroll
    for (int n = 0; n < 4; ++n) bg[n] = *(const bf16x8*)&sB[bcur][br0 + n * 16 * 32];
    __builtin_amdgcn_s_setprio(1);
#pragma unroll
    for (int m = 0; m < 4; ++m)
#pragma unroll
      for (int n = 0; n < 4; ++n) acc[m][n] = mfma16(af[m], bg[n], acc[m][n]);
    __builtin_amdgcn_s_setprio(0);
    bcur = (bcur == 2) ? 0 : bcur + 1;
  }
#undef QSTAGE

  const int fq4 = (l >> 4) * 4;
#pragma unroll
  for (int n = 0; n < 4; ++n) {
    const int col = n0 + wc * 64 + n * 16 + fr;
    const int sect = col >> 10, c = col & 1023;
    const int hh = c >> 6, d = c & 63;
    const float bvl = (sect == 0 ? bq : sect == 1 ? bk : bv)[c];
#pragma unroll
    for (int m = 0; m < 4; ++m) {
      const int row0 = m0 + wr * 64 + m * 16 + fq4;
#pragma unroll
      for (int j = 0; j < 4; ++j) {
        const int row = row0 + j;
        const int b = row >> 11, t = row & (Tt - 1);
        const float v = acc[m][n][j] + bvl;
        if (sect < 2) {
          unsigned short* dst = sect ? Ko : Qo;
          dst[((size_t)(b * Hh + hh) * Tt + t) * DHc + d] = f2bf(v);
        } else {
          Vo[((size_t)(b * Hh + hh) * DHc + d) * Tt + t] = f2bf(v);
        }
      }
    }
  }
}

// ---------------------------------------------------------------- small GEMM (BN=64)
// C[4096,1024] = A @ Bt^T + bias; 128x64 tile, BK=64, 4 waves (2x2), 512 blocks (2/CU)
// 3-deep rotating LDS buffers, counted vmcnt, XOR-swizzled LDS (T2).
// MODE 2: v += add32[idx] (x residual, f32); h16 = bf16(v)      (Wo)
// MODE 3: v = leaky_relu(v); out16 = bf16(v)                     (Wh)
// MODE 4: v += bf2f(add16[idx]) (h residual, bf16); out32 = v    (Wy -> d_out)
template <int MODE>
__global__ __launch_bounds__(256, 2) void k_gemm2(
    const unsigned short* __restrict__ A, const unsigned short* __restrict__ Bt,
    const float* __restrict__ bias, const float* __restrict__ add32,
    const unsigned short* __restrict__ add16,
    float* __restrict__ out32, unsigned short* __restrict__ out16) {
  constexpr int K = Dd, N = Dd;
  constexpr int NT = K / 64;  // 16
  __shared__ unsigned short sA[3][128 * 64];
  __shared__ unsigned short sB[3][64 * 64];
  const int tid = threadIdx.x;
  const int w = tid >> 6, l = tid & 63;
  const int wr = w >> 1, wc = w & 1;
  const int m0 = blockIdx.y * 128, n0b = blockIdx.x * 64;

  const f32x4 fz = {0.f, 0.f, 0.f, 0.f};
  f32x4 acc[4][2];
#pragma unroll
  for (int m = 0; m < 4; ++m)
#pragma unroll
    for (int n = 0; n < 2; ++n) acc[m][n] = fz;

  const int ssw = (((l & 7) * 16) ^ ((l >> 3) << 4));
  const char* paB = (const char*)(A + (size_t)(m0 + w * 32 + (l >> 3)) * K) + ssw;
  const char* pbB = (const char*)(Bt + (size_t)(n0b + w * 16 + (l >> 3)) * K) + ssw;

#define GSTAGE(tt, bb)                                                   \
  do {                                                                   \
    char* laB = (char*)sA[bb] + (w * 32) * 128;                          \
    char* lbB = (char*)sB[bb] + (w * 16) * 128;                          \
    const size_t ko = (size_t)(tt) * 128;                                \
    gload16(paB + ko, laB);                                              \
    gload16(paB + ko + (size_t)16 * Dd, laB + 1024);                     \
    gload16(paB + ko + (size_t)32 * Dd, laB + 2048);                     \
    gload16(paB + ko + (size_t)48 * Dd, laB + 3072);                     \
    gload16(pbB + ko, lbB);                                              \
    gload16(pbB + ko + (size_t)16 * Dd, lbB + 1024);                     \
  } while (0)

  GSTAGE(0, 0);
  GSTAGE(1, 1);
  int bcur = 0;

  const int fr = l & 15, fkb = (l >> 4) * 16;  // frag row, frag k byte
  const int rsw = (l & 7) << 4;                // read swizzle (row&7 == l&7)
  const int arB = (wr * 64 + fr) * 128;        // A frag row byte base
  const int brB = (wc * 32 + fr) * 128;        // B frag row byte base

  for (int t = 0; t < NT; ++t) {
    if (t < NT - 1) {
      asm volatile("s_waitcnt vmcnt(6)" ::: "memory");
    } else {
      asm volatile("s_waitcnt vmcnt(0)" ::: "memory");
    }
    __builtin_amdgcn_s_barrier();
    __builtin_amdgcn_sched_barrier(0);
    if (t + 2 < NT) {
      const int b2 = (bcur + 2 >= 3) ? bcur - 1 : bcur + 2;
      GSTAGE(t + 2, b2);
    }
    const char* ab = (const char*)sA[bcur];
    const char* bb2 = (const char*)sB[bcur];
    bf16x8 af[4][2], bg[2][2];
#pragma unroll
    for (int m = 0; m < 4; ++m) {
      af[m][0] = *(const bf16x8*)(ab + arB + m * 16 * 128 + ((0 + fkb) ^ rsw));
      af[m][1] = *(const bf16x8*)(ab + arB + m * 16 * 128 + ((64 + fkb) ^ rsw));
    }
#pragma unroll
    for (int n = 0; n < 2; ++n) {
      bg[n][0] = *(const bf16x8*)(bb2 + brB + n * 16 * 128 + ((0 + fkb) ^ rsw));
      bg[n][1] = *(const bf16x8*)(bb2 + brB + n * 16 * 128 + ((64 + fkb) ^ rsw));
    }
    __builtin_amdgcn_s_setprio(1);
#pragma unroll
    for (int m = 0; m < 4; ++m)
#pragma unroll
      for (int n = 0; n < 2; ++n) {
        acc[m][n] = mfma16(af[m][0], bg[n][0], acc[m][n]);
        acc[m][n] = mfma16(af[m][1], bg[n][1], acc[m][n]);
      }
    __builtin_amdgcn_s_setprio(0);
    bcur = (bcur == 2) ? 0 : bcur + 1;
  }
#undef GSTAGE

  const int fq4 = (l >> 4) * 4;
#pragma unroll
  for (int n = 0; n < 2; ++n) {
    const int col = n0b + wc * 32 + n * 16 + fr;
    const float bvl = bias[col];
#pragma unroll
    for (int m = 0; m < 4; ++m) {
      const int row0 = m0 + wr * 64 + m * 16 + fq4;
#pragma unroll
      for (int j = 0; j < 4; ++j) {
        const int row = row0 + j;
        const size_t idx = (size_t)row * N + col;
        float v = acc[m][n][j] + bvl;
        if constexpr (MODE == 2) {
          v += add32[idx];
          out16[idx] = f2bf(v);
        } else if constexpr (MODE == 3) {
          v = v > 0.f ? v : 0.01f * v;
          out16[idx] = f2bf(v);
        } else {
          v += bf2f(add16[idx]);
          out32[idx] = v;
        }
      }
    }
  }
}

// ---------------------------------------------------------------- attention
// Q,K: [BH][T][64] bf16; Vt: [BH][64][T] bf16; ctx out: [B][T][D] bf16
// 256 blocks (8 q-tiles x 32 bh), 8 waves/block (512 thr), wave owns 32 q-rows.
// Same 64KB K/V LDS shared by 8 waves -> 2 blocks/CU = 16 waves/CU (4/SIMD,
// 2x round-13 occupancy). Each thread stages ONE 16B chunk of K and V per tile.
// Deferred-softmax pipeline, x4-unrolled static LDS indices, counted vmcnt.
__global__ __launch_bounds__(512, 4) void k_attn(const unsigned short* __restrict__ Q,
                                                 const unsigned short* __restrict__ Km,
                                                 const unsigned short* __restrict__ Vt,
                                                 unsigned short* __restrict__ ctx) {
  __shared__ unsigned short sK[4][64 * 64];
  __shared__ unsigned short sV[4][64 * 64];

  // bijective XCD swizzle: 256 blocks, 8 XCDs -> 4 heads' blocks per XCD
  const int pid = blockIdx.x;
  const int logical = (pid & 7) * 32 + (pid >> 3);
  const int bh = logical >> 3;
  const int qt = logical & 7;

  const int w = threadIdx.x >> 6, l = threadIdx.x & 63;
  const int h = l >> 5, lq = l & 31;
  const int q0w = qt * 256 + w * 32;

  const unsigned short* Qb = Q + (size_t)bh * Tt * DHc;
  const char* Kb = (const char*)(Km + (size_t)bh * Tt * DHc);
  const char* Vb = (const char*)(Vt + (size_t)bh * DHc * Tt);

  // Q^T B-frags: lane needs Q[q0w+lq][cs*16 + h*8 + e]
  bf16x8 qf[4];
  {
    const unsigned short* Qrow = Qb + (size_t)(q0w + lq) * DHc;
#pragma unroll
    for (int cs = 0; cs < 4; ++cs) qf[cs] = *(const bf16x8*)&Qrow[cs * 16 + h * 8];
  }

  // staging: thread (w,l) stages chunk c = w*64+l -> tile row r0 = c>>3
  const int r0 = w * 8 + (l >> 3);
  const int s0o = ((l & 7) * 16) ^ (((l >> 3) & 7) << 4);  // swizzled byte-in-row
  char* dK0 = (char*)sK[0] + (size_t)w * 1024;  // wave-uniform LDS base
  char* dV0 = (char*)sV[0] + (size_t)w * 1024;

#define STAGE(tt, bb)                                                      \
  do {                                                                     \
    const size_t bs = (size_t)(bb) * 8192;                                 \
    gload16(Kb + (size_t)(tt) * 8192 + (size_t)r0 * 128 + s0o, dK0 + bs);  \
    gload16(Vb + (size_t)r0 * (Tt * 2) + (size_t)(tt) * 128 + s0o, dV0 + bs); \
  } while (0)

  const int swl = (lq & 7) << 4;  // read swizzle: rows lq and lq+32 share (row&7)

#define QKC(bufi, d0, d1)                                                  \
  do {                                                                     \
    const char* kb_ = (const char*)sK[bufi];                               \
    const char* kr0_ = kb_ + lq * 128;                                     \
    const char* kr1_ = kb_ + (32 + lq) * 128;                              \
    __builtin_amdgcn_s_setprio(1);                                         \
    _Pragma("unroll") for (int cs = 0; cs < 4; ++cs) {                     \
      const int cb = (cs * 32 + h * 16) ^ swl;                             \
      d0 = mfma32(*(const bf16x8*)(kr0_ + cb), qf[cs], d0);                \
      d1 = mfma32(*(const bf16x8*)(kr1_ + cb), qf[cs], d1);                \
    }                                                                      \
    __builtin_amdgcn_s_setprio(0);                                         \
  } while (0)

  f32x16 o0 = {}, o1 = {};
  float mr = -3e38f, lr = 0.f, em = 0.f;
  constexpr float C2 = 0.18033688011112042f;  // 0.125 * log2(e)
  constexpr int NT = Tt / 64;  // 32

  STAGE(0, 0);
  STAGE(1, 1);
  STAGE(2, 2);
  asm volatile("s_waitcnt vmcnt(4)" ::: "memory");  // 6 in flight -> tile 0 done
  __builtin_amdgcn_s_barrier();
  __builtin_amdgcn_sched_barrier(0);

  f32x16 pA0 = {}, pA1 = {}, pB0 = {}, pB1 = {};
  QKC(0, pA0, pA1);  // scores for tile 0

  // vb/nb/sb are always called with literals -> LDS addresses fold statically
  auto body = [&](int t, int vb, int nb, int sb, f32x16& cc0, f32x16& cc1,
                  f32x16& nn0, f32x16& nn1) {
    if (t < NT - 2) {
      asm volatile("s_waitcnt vmcnt(2)" ::: "memory");  // t & t+1 arrived
    } else {
      asm volatile("s_waitcnt vmcnt(0)" ::: "memory");
    }
    __builtin_amdgcn_s_barrier();
    __builtin_amdgcn_sched_barrier(0);

    if (t + 3 < NT) STAGE(t + 3, sb);

    // ---- QK(t+1) on the MFMA pipe (independent of softmax below)
    if (t + 1 < NT) {
      nn0 = {};
      nn1 = {};
      QKC(nb, nn0, nn1);
    }

    // ---- online softmax(t) (q lane-local; raw scores, 0.125 folded into C2)
    float t0[8];
#pragma unroll
    for (int r = 0; r < 8; ++r)
      t0[r] = fmaxf(fmaxf(cc0[r], cc0[r + 8]), fmaxf(cc1[r], cc1[r + 8]));
#pragma unroll
    for (int r = 0; r < 4; ++r) t0[r] = fmaxf(t0[r], t0[r + 4]);
    const float smax = fmaxf(fmaxf(t0[0], t0[1]), fmaxf(t0[2], t0[3]));

    if (!__all(smax <= mr + 64.f)) {
      const float sp = fmaxf(smax, __shfl_xor(smax, 32));
      const float mn = fmaxf(mr, sp);
      const float sc = exp2g((mr - mn) * C2);
      mr = mn;
      em = mr * C2;
      lr *= sc;
#pragma unroll
      for (int r = 0; r < 16; ++r) { o0[r] *= sc; o1[r] *= sc; }
    }
    float rsa[4] = {0.f, 0.f, 0.f, 0.f};
#pragma unroll
    for (int r = 0; r < 16; ++r) {
      const float p0 = exp2g(__builtin_fmaf(cc0[r], C2, -em));
      const float p1 = exp2g(__builtin_fmaf(cc1[r], C2, -em));
      cc0[r] = p0; cc1[r] = p1;
      rsa[r & 3] += p0 + p1;
    }
    lr += (rsa[0] + rsa[1]) + (rsa[2] + rsa[3]);  // lane-half partial

    // ---- pack P^T to bf16 B-frags (cvt_pk + permlane32_swap)
    union Uv { unsigned u[4]; bf16x8 v; } uu;
    bf16x8 pbv[4];
    {
      unsigned a = cvtpk(cc0[0], cc0[1]), b2 = cvtpk(cc0[2], cc0[3]);
      unsigned c = cvtpk(cc0[4], cc0[5]), d2 = cvtpk(cc0[6], cc0[7]);
      plswap(c, a); plswap(d2, b2);
      uu.u[0] = a; uu.u[1] = b2; uu.u[2] = c; uu.u[3] = d2; pbv[0] = uu.v;
      unsigned e = cvtpk(cc0[8], cc0[9]), f = cvtpk(cc0[10], cc0[11]);
      unsigned g = cvtpk(cc0[12], cc0[13]), h2 = cvtpk(cc0[14], cc0[15]);
      plswap(g, e); plswap(h2, f);
      uu.u[0] = e; uu.u[1] = f; uu.u[2] = g; uu.u[3] = h2; pbv[1] = uu.v;
    }
    {
      unsigned a = cvtpk(cc1[0], cc1[1]), b2 = cvtpk(cc1[2], cc1[3]);
      unsigned c = cvtpk(cc1[4], cc1[5]), d2 = cvtpk(cc1[6], cc1[7]);
      plswap(c, a); plswap(d2, b2);
      uu.u[0] = a; uu.u[1] = b2; uu.u[2] = c; uu.u[3] = d2; pbv[2] = uu.v;
      unsigned e = cvtpk(cc1[8], cc1[9]), f = cvtpk(cc1[10], cc1[11]);
      unsigned g = cvtpk(cc1[12], cc1[13]), h2 = cvtpk(cc1[14], cc1[15]);
      plswap(g, e); plswap(h2, f);
      uu.u[0] = e; uu.u[1] = f; uu.u[2] = g; uu.u[3] = h2; pbv[3] = uu.v;
    }

    // ---- O^T += V . P^T
    const char* vbuf = (const char*)sV[vb];
    const char* vrow0 = vbuf + lq * 128;
    const char* vrow1 = vbuf + (32 + lq) * 128;
    __builtin_amdgcn_s_setprio(1);
    o0 = mfma32(*(const bf16x8*)(vrow0 + ((0 + h * 16) ^ swl)), pbv[0], o0);
    o0 = mfma32(*(const bf16x8*)(vrow0 + ((32 + h * 16) ^ swl)), pbv[1], o0);
    o0 = mfma32(*(const bf16x8*)(vrow0 + ((64 + h * 16) ^ swl)), pbv[2], o0);
    o0 = mfma32(*(const bf16x8*)(vrow0 + ((96 + h * 16) ^ swl)), pbv[3], o0);
    o1 = mfma32(*(const bf16x8*)(vrow1 + ((0 + h * 16) ^ swl)), pbv[0], o1);
    o1 = mfma32(*(const bf16x8*)(vrow1 + ((32 + h * 16) ^ swl)), pbv[1], o1);
    o1 = mfma32(*(const bf16x8*)(vrow1 + ((64 + h * 16) ^ swl)), pbv[2], o1);
    o1 = mfma32(*(const bf16x8*)(vrow1 + ((96 + h * 16) ^ swl)), pbv[3], o1);
    __builtin_amdgcn_s_setprio(0);
  };

#pragma unroll 1
  for (int tp = 0; tp < NT; tp += 4) {
    body(tp + 0, 0, 1, 3, pA0, pA1, pB0, pB1);
    body(tp + 1, 1, 2, 0, pB0, pB1, pA0, pA1);
    body(tp + 2, 2, 3, 1, pA0, pA1, pB0, pB1);
    body(tp + 3, 3, 0, 2, pB0, pB1, pA0, pA1);
  }
#undef STAGE
#undef QKC

  // ---- epilogue: merge lane-half denominators, O^T[d][q]/lr -> ctx
  const float lrt = lr + __shfl_xor(lr, 32);
  const int b = bh >> 4, hh = bh & 15;
  unsigned short* crow = ctx + ((size_t)(b * Tt + q0w + lq)) * Dd + hh * DHc;
  const float inv = 1.f / lrt;
#pragma unroll
  for (int r = 0; r < 16; r += 2) {
    const int d = (r & 3) + 8 * (r >> 2) + 4 * h;
    const unsigned u0 = cvtpk(o0[r] * inv, o0[r + 1] * inv);
    const unsigned u1 = cvtpk(o1[r] * inv, o1[r + 1] * inv);
    *(unsigned*)(crow + d) = u0;
    *(unsigned*)(crow + 32 + d) = u1;
  }
}

// ---------------------------------------------------------------- launch
extern "C" void kernel_launch(void* const* d_in, const int* in_sizes, int n_in,
                              void* d_out, int out_size, void* d_ws, size_t ws_size,
                              hipStream_t stream) {
  (void)in_sizes; (void)n_in; (void)out_size; (void)ws_size;
  const float* x   = (const float*)d_in[0];
  const float* Wq  = (const float*)d_in[1];
  const float* bq  = (const float*)d_in[2];
  const float* Wk  = (const float*)d_in[3];
  const float* bk  = (const float*)d_in[4];
  const float* Wv  = (const float*)d_in[5];
  const float* bv  = (const float*)d_in[6];
  const float* Wo  = (const float*)d_in[7];
  const float* bo  = (const float*)d_in[8];
  const float* Wh  = (const float*)d_in[9];
  const float* bhi = (const float*)d_in[10];
  const float* Wy  = (const float*)d_in[11];
  const float* by  = (const float*)d_in[12];
  float* out = (float*)d_out;

  const size_t EL = (size_t)BT * Dd;  // 4M elements
  const size_t M1 = (size_t)Dd * Dd;  // 1M elements
  unsigned short* slotA = (unsigned short*)d_ws;  // 8MB : x16 -> ctx16 -> act16
  unsigned short* slotB = slotA + EL;             // 8MB : Q16 -> h16
  unsigned short* slotC = slotB + EL;             // 16MB: K16+Vt16
  unsigned short* wts   = slotC + 2 * EL;         // 12MB: [Wqkv^T 3M][Wo^T][Wh^T][Wy^T]
  unsigned short* WqkvT = wts;
  unsigned short* WoT   = wts + 3 * M1;
  unsigned short* WhT   = wts + 4 * M1;
  unsigned short* WyT   = wts + 5 * M1;

  unsigned short* x16   = slotA;
  unsigned short* Q16   = slotB;
  unsigned short* K16   = slotC;
  unsigned short* Vt16  = slotC + EL;
  unsigned short* ctx16 = slotA;            // x16 dead after QKV GEMM
  unsigned short* h16   = slotB;            // Q16 dead after attention
  unsigned short* act16 = slotA;            // ctx16 dead after Wo GEMM

  k_prep<<<dim3(32, 32, 7), dim3(32, 8), 0, stream>>>(x, Wq, Wk, Wv, Wo, Wh, Wy, wts, x16);

  k_gemm_qkv<<<dim3(768), 256, 0, stream>>>(x16, WqkvT, bq, bk, bv, Q16, K16, Vt16);

  k_attn<<<dim3(256), 512, 0, stream>>>(Q16, K16, Vt16, ctx16);

  const dim3 g2(16, 32);
  k_gemm2<2><<<g2, 256, 0, stream>>>(ctx16, WoT, bo, x, nullptr, nullptr, h16);
  k_gemm2<3><<<g2, 256, 0, stream>>>(h16, WhT, bhi, nullptr, nullptr, nullptr, act16);
  k_gemm2<4><<<g2, 256, 0, stream>>>(act16, WyT, by, nullptr, h16, out, nullptr);
}

// Round 16
// 150.676 us; speedup vs baseline: 1.6849x; 1.6849x over previous
//
#include <hip/hip_runtime.h>
#include <cstdint>
#include <cstddef>

#define DEV __device__ __forceinline__

typedef __attribute__((ext_vector_type(8))) short bf16x8;    // 8 bf16 = 4 VGPRs
typedef __attribute__((ext_vector_type(4))) float f32x4;
typedef __attribute__((ext_vector_type(16))) float f32x16;

static_assert(sizeof(bf16x8) == 16, "frag size");

static constexpr int Bb = 2, Tt = 2048, Dd = 1024, Hh = 16, DHc = 64;
static constexpr int BT = Bb * Tt;  // 4096

DEV unsigned short f2bf(float f) {
  union { float f; unsigned u; } v; v.f = f;
  unsigned r = v.u + 0x7fffu + ((v.u >> 16) & 1u);  // RNE
  return (unsigned short)(r >> 16);
}
DEV float bf2f(unsigned short u) {
  union { unsigned u; float f; } v; v.u = (unsigned)u << 16;
  return v.f;
}

DEV void gload16(const void* g, void* l) {
  __builtin_amdgcn_global_load_lds((__attribute__((address_space(1))) void*)(g),
                                   (__attribute__((address_space(3))) void*)(l),
                                   16, 0, 0);
}

DEV f32x4 mfma16(bf16x8 a, bf16x8 b, f32x4 c) {
  return __builtin_amdgcn_mfma_f32_16x16x32_bf16(a, b, c, 0, 0, 0);
}
DEV f32x16 mfma32(bf16x8 a, bf16x8 b, f32x16 c) {
  return __builtin_amdgcn_mfma_f32_32x32x16_bf16(a, b, c, 0, 0, 0);
}

DEV unsigned cvtpk(float lo, float hi) {
  unsigned r;
  asm("v_cvt_pk_bf16_f32 %0, %1, %2" : "=v"(r) : "v"(lo), "v"(hi));
  return r;
}
DEV void plswap(unsigned& x, unsigned& y) {
  asm volatile("v_permlane32_swap_b32 %0, %1" : "+v"(x), "+v"(y));
}
DEV float exp2g(float x) {
#if __has_builtin(__builtin_amdgcn_exp2f)
  return __builtin_amdgcn_exp2f(x);
#else
  return exp2f(x);
#endif
}

// ---------------------------------------------------------------- prep
// z<6: transpose W[z] -> bf16 W^T slab; z==6: convert x -> bf16
__global__ __launch_bounds__(256) void k_prep(
    const float* __restrict__ x, const float* __restrict__ W0,
    const float* __restrict__ W1, const float* __restrict__ W2,
    const float* __restrict__ W3, const float* __restrict__ W4,
    const float* __restrict__ W5, unsigned short* __restrict__ wtsBase,
    unsigned short* __restrict__ x16) {
  const int z = blockIdx.z;
  const int tx = threadIdx.x, ty = threadIdx.y;  // block (32,8)
  if (z == 6) {
    const int flat = blockIdx.y * 32 + blockIdx.x;
    const int tid = ty * 32 + tx;
    const float4* x4 = (const float4*)x;
    ushort4* o4 = (ushort4*)x16;
#pragma unroll
    for (int u = 0; u < 4; ++u) {
      const int i = flat * 1024 + u * 256 + tid;
      float4 v = x4[i];
      ushort4 o;
      o.x = f2bf(v.x); o.y = f2bf(v.y); o.z = f2bf(v.z); o.w = f2bf(v.w);
      o4[i] = o;
    }
    return;
  }
  __shared__ float t[32][33];
  const float* W = z == 0 ? W0 : z == 1 ? W1 : z == 2 ? W2 : z == 3 ? W3 : z == 4 ? W4 : W5;
  unsigned short* Wt = wtsBase + (size_t)z * Dd * Dd;
  const int n0 = blockIdx.x * 32, k0 = blockIdx.y * 32;
#pragma unroll
  for (int i = 0; i < 4; ++i)
    t[ty + 8 * i][tx] = W[(size_t)(k0 + ty + 8 * i) * Dd + n0 + tx];
  __syncthreads();
#pragma unroll
  for (int i = 0; i < 4; ++i)
    Wt[(size_t)(n0 + ty + 8 * i) * Dd + k0 + tx] = f2bf(t[tx][ty + 8 * i]);
}

// ---------------------------------------------------------------- fused QKV GEMM
// C[4096,3072] = x16 @ Wqkv^T + bias; 128x128 tile, BK=32, 4 waves,
// 768 blocks (3/CU), 1D grid with bijective XCD swizzle (chunk=96).
// 3-deep rotating LDS buffers, counted vmcnt, one barrier per K-step.
__global__ __launch_bounds__(256, 3) void k_gemm_qkv(
    const unsigned short* __restrict__ A, const unsigned short* __restrict__ Bt,
    const float* __restrict__ bq, const float* __restrict__ bk,
    const float* __restrict__ bv, unsigned short* __restrict__ Qo,
    unsigned short* __restrict__ Ko, unsigned short* __restrict__ Vo) {
  constexpr int K = Dd;
  constexpr int NT = K / 32;  // 32
  __shared__ unsigned short sA[3][128 * 32];
  __shared__ unsigned short sB[3][128 * 32];
  const int tid = threadIdx.x;
  const int w = tid >> 6, l = tid & 63;
  const int wr = w >> 1, wc = w & 1;
  // XCD swizzle: 768 blocks, 8 XCDs -> 96 logical ids per XCD (4 rows x 24 cols)
  const int pid = blockIdx.x;
  const int logical = (pid & 7) * 96 + (pid >> 3);
  const int m0 = (logical / 24) * 128, n0 = (logical % 24) * 128;

  const f32x4 fz = {0.f, 0.f, 0.f, 0.f};
  f32x4 acc[4][4];
#pragma unroll
  for (int m = 0; m < 4; ++m)
#pragma unroll
    for (int n = 0; n < 4; ++n) acc[m][n] = fz;

  const int srow = l >> 2, scol = (l & 3) * 8;
  const unsigned short* pa = A + (size_t)(m0 + w * 32 + srow) * K + scol;
  const unsigned short* pb = Bt + (size_t)(n0 + w * 32 + srow) * K + scol;
  const int fr = l & 15, fk = (l >> 4) * 8;
  const int ar0 = (wr * 64 + fr) * 32 + fk;
  const int br0 = (wc * 64 + fr) * 32 + fk;

#define QSTAGE(tt, bb)                                            \
  do {                                                            \
    unsigned short* la = &sA[bb][(w * 32) * 32];                  \
    unsigned short* lb = &sB[bb][(w * 32) * 32];                  \
    gload16(pa + (tt) * 32, la);                                  \
    gload16(pa + (tt) * 32 + (size_t)16 * K, la + 16 * 32);       \
    gload16(pb + (tt) * 32, lb);                                  \
    gload16(pb + (tt) * 32 + (size_t)16 * K, lb + 16 * 32);       \
  } while (0)

  QSTAGE(0, 0);
  QSTAGE(1, 1);
  int bcur = 0;

  for (int t = 0; t < NT; ++t) {
    if (t < NT - 1) {
      asm volatile("s_waitcnt vmcnt(4)" ::: "memory");
    } else {
      asm volatile("s_waitcnt vmcnt(0)" ::: "memory");
    }
    __builtin_amdgcn_s_barrier();
    __builtin_amdgcn_sched_barrier(0);
    if (t + 2 < NT) {
      const int b2 = (bcur + 2 >= 3) ? bcur - 1 : bcur + 2;
      QSTAGE(t + 2, b2);
    }
    bf16x8 af[4], bg[4];
#pragma unroll
    for (int m = 0; m < 4; ++m) af[m] = *(const bf16x8*)&sA[bcur][ar0 + m * 16 * 32];
#pragma unroll
    for (int n = 0; n < 4; ++n) bg[n] = *(const bf16x8*)&sB[bcur][br0 + n * 16 * 32];
    __builtin_amdgcn_s_setprio(1);
#pragma unroll
    for (int m = 0; m < 4; ++m)
#pragma unroll
      for (int n = 0; n < 4; ++n) acc[m][n] = mfma16(af[m], bg[n], acc[m][n]);
    __builtin_amdgcn_s_setprio(0);
    bcur = (bcur == 2) ? 0 : bcur + 1;
  }
#undef QSTAGE

  const int fq4 = (l >> 4) * 4;
#pragma unroll
  for (int n = 0; n < 4; ++n) {
    const int col = n0 + wc * 64 + n * 16 + fr;
    const int sect = col >> 10, c = col & 1023;
    const int hh = c >> 6, d = c & 63;
    const float bvl = (sect == 0 ? bq : sect == 1 ? bk : bv)[c];
#pragma unroll
    for (int m = 0; m < 4; ++m) {
      const int row0 = m0 + wr * 64 + m * 16 + fq4;
#pragma unroll
      for (int j = 0; j < 4; ++j) {
        const int row = row0 + j;
        const int b = row >> 11, t = row & (Tt - 1);
        const float v = acc[m][n][j] + bvl;
        if (sect < 2) {
          unsigned short* dst = sect ? Ko : Qo;
          dst[((size_t)(b * Hh + hh) * Tt + t) * DHc + d] = f2bf(v);
        } else {
          Vo[((size_t)(b * Hh + hh) * DHc + d) * Tt + t] = f2bf(v);
        }
      }
    }
  }
}

// ---------------------------------------------------------------- small GEMM (BN=64)
// C[4096,1024] = A @ Bt^T + bias; 128x64 tile, BK=64, 4 waves (2x2),
// 512 blocks (2/CU), 1D grid with bijective XCD swizzle (chunk=64: each XCD
// owns 4 contiguous A-row-panels -> A L2-resident per XCD).
// 3-deep rotating LDS buffers, counted vmcnt, XOR-swizzled LDS (T2).
// MODE 2: v += add32[idx] (x residual, f32); h16 = bf16(v)      (Wo)
// MODE 3: v = leaky_relu(v); out16 = bf16(v)                     (Wh)
// MODE 4: v += bf2f(add16[idx]) (h residual, bf16); out32 = v    (Wy -> d_out)
template <int MODE>
__global__ __launch_bounds__(256, 2) void k_gemm2(
    const unsigned short* __restrict__ A, const unsigned short* __restrict__ Bt,
    const float* __restrict__ bias, const float* __restrict__ add32,
    const unsigned short* __restrict__ add16,
    float* __restrict__ out32, unsigned short* __restrict__ out16) {
  constexpr int K = Dd, N = Dd;
  constexpr int NT = K / 64;  // 16
  __shared__ unsigned short sA[3][128 * 64];
  __shared__ unsigned short sB[3][64 * 64];
  const int tid = threadIdx.x;
  const int w = tid >> 6, l = tid & 63;
  const int wr = w >> 1, wc = w & 1;
  // XCD swizzle: 512 blocks, 8 XCDs -> 64 logical ids per XCD (4 rows x 16 cols)
  const int pid = blockIdx.x;
  const int logical = (pid & 7) * 64 + (pid >> 3);
  const int m0 = (logical >> 4) * 128, n0b = (logical & 15) * 64;

  const f32x4 fz = {0.f, 0.f, 0.f, 0.f};
  f32x4 acc[4][2];
#pragma unroll
  for (int m = 0; m < 4; ++m)
#pragma unroll
    for (int n = 0; n < 2; ++n) acc[m][n] = fz;

  const int ssw = (((l & 7) * 16) ^ ((l >> 3) << 4));
  const char* paB = (const char*)(A + (size_t)(m0 + w * 32 + (l >> 3)) * K) + ssw;
  const char* pbB = (const char*)(Bt + (size_t)(n0b + w * 16 + (l >> 3)) * K) + ssw;

#define GSTAGE(tt, bb)                                                   \
  do {                                                                   \
    char* laB = (char*)sA[bb] + (w * 32) * 128;                          \
    char* lbB = (char*)sB[bb] + (w * 16) * 128;                          \
    const size_t ko = (size_t)(tt) * 128;                                \
    gload16(paB + ko, laB);                                              \
    gload16(paB + ko + (size_t)16 * Dd, laB + 1024);                     \
    gload16(paB + ko + (size_t)32 * Dd, laB + 2048);                     \
    gload16(paB + ko + (size_t)48 * Dd, laB + 3072);                     \
    gload16(pbB + ko, lbB);                                              \
    gload16(pbB + ko + (size_t)16 * Dd, lbB + 1024);                     \
  } while (0)

  GSTAGE(0, 0);
  GSTAGE(1, 1);
  int bcur = 0;

  const int fr = l & 15, fkb = (l >> 4) * 16;  // frag row, frag k byte
  const int rsw = (l & 7) << 4;                // read swizzle (row&7 == l&7)
  const int arB = (wr * 64 + fr) * 128;        // A frag row byte base
  const int brB = (wc * 32 + fr) * 128;        // B frag row byte base

  for (int t = 0; t < NT; ++t) {
    if (t < NT - 1) {
      asm volatile("s_waitcnt vmcnt(6)" ::: "memory");
    } else {
      asm volatile("s_waitcnt vmcnt(0)" ::: "memory");
    }
    __builtin_amdgcn_s_barrier();
    __builtin_amdgcn_sched_barrier(0);
    if (t + 2 < NT) {
      const int b2 = (bcur + 2 >= 3) ? bcur - 1 : bcur + 2;
      GSTAGE(t + 2, b2);
    }
    const char* ab = (const char*)sA[bcur];
    const char* bb2 = (const char*)sB[bcur];
    bf16x8 af[4][2], bg[2][2];
#pragma unroll
    for (int m = 0; m < 4; ++m) {
      af[m][0] = *(const bf16x8*)(ab + arB + m * 16 * 128 + ((0 + fkb) ^ rsw));
      af[m][1] = *(const bf16x8*)(ab + arB + m * 16 * 128 + ((64 + fkb) ^ rsw));
    }
#pragma unroll
    for (int n = 0; n < 2; ++n) {
      bg[n][0] = *(const bf16x8*)(bb2 + brB + n * 16 * 128 + ((0 + fkb) ^ rsw));
      bg[n][1] = *(const bf16x8*)(bb2 + brB + n * 16 * 128 + ((64 + fkb) ^ rsw));
    }
    __builtin_amdgcn_s_setprio(1);
#pragma unroll
    for (int m = 0; m < 4; ++m)
#pragma unroll
      for (int n = 0; n < 2; ++n) {
        acc[m][n] = mfma16(af[m][0], bg[n][0], acc[m][n]);
        acc[m][n] = mfma16(af[m][1], bg[n][1], acc[m][n]);
      }
    __builtin_amdgcn_s_setprio(0);
    bcur = (bcur == 2) ? 0 : bcur + 1;
  }
#undef GSTAGE

  const int fq4 = (l >> 4) * 4;
#pragma unroll
  for (int n = 0; n < 2; ++n) {
    const int col = n0b + wc * 32 + n * 16 + fr;
    const float bvl = bias[col];
#pragma unroll
    for (int m = 0; m < 4; ++m) {
      const int row0 = m0 + wr * 64 + m * 16 + fq4;
#pragma unroll
      for (int j = 0; j < 4; ++j) {
        const int row = row0 + j;
        const size_t idx = (size_t)row * N + col;
        float v = acc[m][n][j] + bvl;
        if constexpr (MODE == 2) {
          v += add32[idx];
          out16[idx] = f2bf(v);
        } else if constexpr (MODE == 3) {
          v = v > 0.f ? v : 0.01f * v;
          out16[idx] = f2bf(v);
        } else {
          v += bf2f(add16[idx]);
          out32[idx] = v;
        }
      }
    }
  }
}

// ---------------------------------------------------------------- attention
// Q,K: [BH][T][64] bf16; Vt: [BH][64][T] bf16; ctx out: [B][T][D] bf16
// 512 blocks (16 q-tiles x 32 bh), 4 waves, wave owns 32 q-rows.
// Deferred-softmax pipeline; main loop unrolled x4 so ALL LDS buffer indices
// are compile-time literals (addresses loop-invariant / folded into offsets).
// 4 rotating LDS buffers, counted vmcnt (2 stages in flight), 1 barrier/tile.
__global__ __launch_bounds__(256, 2) void k_attn(const unsigned short* __restrict__ Q,
                                                 const unsigned short* __restrict__ Km,
                                                 const unsigned short* __restrict__ Vt,
                                                 unsigned short* __restrict__ ctx) {
  __shared__ unsigned short sK[4][64 * 64];
  __shared__ unsigned short sV[4][64 * 64];

  // bijective XCD swizzle: 512 blocks, 8 XCDs -> 4 heads' blocks per XCD
  const int pid = blockIdx.x;
  const int logical = (pid & 7) * 64 + (pid >> 3);
  const int bh = logical >> 4;
  const int qt = logical & 15;

  const int w = threadIdx.x >> 6, l = threadIdx.x & 63;
  const int h = l >> 5, lq = l & 31;
  const int q0w = qt * 128 + w * 32;

  const unsigned short* Qb = Q + (size_t)bh * Tt * DHc;
  const char* Kb = (const char*)(Km + (size_t)bh * Tt * DHc);
  const char* Vb = (const char*)(Vt + (size_t)bh * DHc * Tt);

  // Q^T B-frags: lane needs Q[q0w+lq][cs*16 + h*8 + e]
  bf16x8 qf[4];
  {
    const unsigned short* Qrow = Qb + (size_t)(q0w + lq) * DHc;
#pragma unroll
    for (int cs = 0; cs < 4; ++cs) qf[cs] = *(const bf16x8*)&Qrow[cs * 16 + h * 8];
  }

  // staging offsets (swizzled source, linear LDS dest)
  const int c0 = w * 128 + l;
  const int c1 = c0 + 64;
  const int r0 = c0 >> 3, r1 = c1 >> 3;
  const int s0o = ((c0 & 7) * 16) ^ ((r0 & 7) << 4);
  const int s1o = ((c1 & 7) * 16) ^ ((r1 & 7) << 4);
  char* dK0 = (char*)sK[0] + (w * 128) * 16;
  char* dK1 = dK0 + 64 * 16;
  char* dV0 = (char*)sV[0] + (w * 128) * 16;
  char* dV1 = dV0 + 64 * 16;

#define STAGE(tt, bb)                                                      \
  do {                                                                     \
    const size_t kOff = (size_t)(tt) * 8192;                               \
    const size_t vOff = (size_t)(tt) * 128;                                \
    const size_t bs = (size_t)(bb) * 8192;                                 \
    gload16(Kb + kOff + (size_t)r0 * 128 + s0o, dK0 + bs);                 \
    gload16(Kb + kOff + (size_t)r1 * 128 + s1o, dK1 + bs);                 \
    gload16(Vb + (size_t)r0 * (Tt * 2) + vOff + s0o, dV0 + bs);            \
    gload16(Vb + (size_t)r1 * (Tt * 2) + vOff + s1o, dV1 + bs);            \
  } while (0)

  const int swl = (lq & 7) << 4;  // read swizzle: rows lq and lq+32 share (row&7)

#define QKC(bufi, d0, d1)                                                  \
  do {                                                                     \
    const char* kb_ = (const char*)sK[bufi];                               \
    const char* kr0_ = kb_ + lq * 128;                                     \
    const char* kr1_ = kb_ + (32 + lq) * 128;                              \
    __builtin_amdgcn_s_setprio(1);                                         \
    _Pragma("unroll") for (int cs = 0; cs < 4; ++cs) {                     \
      const int cb = (cs * 32 + h * 16) ^ swl;                             \
      d0 = mfma32(*(const bf16x8*)(kr0_ + cb), qf[cs], d0);                \
      d1 = mfma32(*(const bf16x8*)(kr1_ + cb), qf[cs], d1);                \
    }                                                                      \
    __builtin_amdgcn_s_setprio(0);                                         \
  } while (0)

  f32x16 o0 = {}, o1 = {};
  float mr = -3e38f, lr = 0.f, em = 0.f;
  constexpr float C2 = 0.18033688011112042f;  // 0.125 * log2(e)
  constexpr int NT = Tt / 64;  // 32

  STAGE(0, 0);
  STAGE(1, 1);
  STAGE(2, 2);
  asm volatile("s_waitcnt vmcnt(8)" ::: "memory");
  __builtin_amdgcn_s_barrier();
  __builtin_amdgcn_sched_barrier(0);

  f32x16 pA0 = {}, pA1 = {}, pB0 = {}, pB1 = {};
  QKC(0, pA0, pA1);  // scores for tile 0

  // vb/nb/sb are always called with literals -> LDS addresses fold statically
  auto body = [&](int t, int vb, int nb, int sb, f32x16& cc0, f32x16& cc1,
                  f32x16& nn0, f32x16& nn1) {
    if (t < NT - 2) {
      asm volatile("s_waitcnt vmcnt(4)" ::: "memory");
    } else {
      asm volatile("s_waitcnt vmcnt(0)" ::: "memory");
    }
    __builtin_amdgcn_s_barrier();
    __builtin_amdgcn_sched_barrier(0);

    if (t + 3 < NT) STAGE(t + 3, sb);

    // ---- QK(t+1) on the MFMA pipe (independent of softmax below)
    if (t + 1 < NT) {
      nn0 = {};
      nn1 = {};
      QKC(nb, nn0, nn1);
    }

    // ---- online softmax(t) (q lane-local; raw scores, 0.125 folded into C2)
    float t0[8];
#pragma unroll
    for (int r = 0; r < 8; ++r)
      t0[r] = fmaxf(fmaxf(cc0[r], cc0[r + 8]), fmaxf(cc1[r], cc1[r + 8]));
#pragma unroll
    for (int r = 0; r < 4; ++r) t0[r] = fmaxf(t0[r], t0[r + 4]);
    const float smax = fmaxf(fmaxf(t0[0], t0[1]), fmaxf(t0[2], t0[3]));

    if (!__all(smax <= mr + 64.f)) {
      const float sp = fmaxf(smax, __shfl_xor(smax, 32));
      const float mn = fmaxf(mr, sp);
      const float sc = exp2g((mr - mn) * C2);
      mr = mn;
      em = mr * C2;
      lr *= sc;
#pragma unroll
      for (int r = 0; r < 16; ++r) { o0[r] *= sc; o1[r] *= sc; }
    }
    float rsa[4] = {0.f, 0.f, 0.f, 0.f};
#pragma unroll
    for (int r = 0; r < 16; ++r) {
      const float p0 = exp2g(__builtin_fmaf(cc0[r], C2, -em));
      const float p1 = exp2g(__builtin_fmaf(cc1[r], C2, -em));
      cc0[r] = p0; cc1[r] = p1;
      rsa[r & 3] += p0 + p1;
    }
    lr += (rsa[0] + rsa[1]) + (rsa[2] + rsa[3]);  // lane-half partial

    // ---- pack P^T to bf16 B-frags (cvt_pk + permlane32_swap)
    union Uv { unsigned u[4]; bf16x8 v; } uu;
    bf16x8 pbv[4];
    {
      unsigned a = cvtpk(cc0[0], cc0[1]), b2 = cvtpk(cc0[2], cc0[3]);
      unsigned c = cvtpk(cc0[4], cc0[5]), d2 = cvtpk(cc0[6], cc0[7]);
      plswap(c, a); plswap(d2, b2);
      uu.u[0] = a; uu.u[1] = b2; uu.u[2] = c; uu.u[3] = d2; pbv[0] = uu.v;
      unsigned e = cvtpk(cc0[8], cc0[9]), f = cvtpk(cc0[10], cc0[11]);
      unsigned g = cvtpk(cc0[12], cc0[13]), h2 = cvtpk(cc0[14], cc0[15]);
      plswap(g, e); plswap(h2, f);
      uu.u[0] = e; uu.u[1] = f; uu.u[2] = g; uu.u[3] = h2; pbv[1] = uu.v;
    }
    {
      unsigned a = cvtpk(cc1[0], cc1[1]), b2 = cvtpk(cc1[2], cc1[3]);
      unsigned c = cvtpk(cc1[4], cc1[5]), d2 = cvtpk(cc1[6], cc1[7]);
      plswap(c, a); plswap(d2, b2);
      uu.u[0] = a; uu.u[1] = b2; uu.u[2] = c; uu.u[3] = d2; pbv[2] = uu.v;
      unsigned e = cvtpk(cc1[8], cc1[9]), f = cvtpk(cc1[10], cc1[11]);
      unsigned g = cvtpk(cc1[12], cc1[13]), h2 = cvtpk(cc1[14], cc1[15]);
      plswap(g, e); plswap(h2, f);
      uu.u[0] = e; uu.u[1] = f; uu.u[2] = g; uu.u[3] = h2; pbv[3] = uu.v;
    }

    // ---- O^T += V . P^T
    const char* vbuf = (const char*)sV[vb];
    const char* vrow0 = vbuf + lq * 128;
    const char* vrow1 = vbuf + (32 + lq) * 128;
    __builtin_amdgcn_s_setprio(1);
    o0 = mfma32(*(const bf16x8*)(vrow0 + ((0 + h * 16) ^ swl)), pbv[0], o0);
    o0 = mfma32(*(const bf16x8*)(vrow0 + ((32 + h * 16) ^ swl)), pbv[1], o0);
    o0 = mfma32(*(const bf16x8*)(vrow0 + ((64 + h * 16) ^ swl)), pbv[2], o0);
    o0 = mfma32(*(const bf16x8*)(vrow0 + ((96 + h * 16) ^ swl)), pbv[3], o0);
    o1 = mfma32(*(const bf16x8*)(vrow1 + ((0 + h * 16) ^ swl)), pbv[0], o1);
    o1 = mfma32(*(const bf16x8*)(vrow1 + ((32 + h * 16) ^ swl)), pbv[1], o1);
    o1 = mfma32(*(const bf16x8*)(vrow1 + ((64 + h * 16) ^ swl)), pbv[2], o1);
    o1 = mfma32(*(const bf16x8*)(vrow1 + ((96 + h * 16) ^ swl)), pbv[3], o1);
    __builtin_amdgcn_s_setprio(0);
  };

#pragma unroll 1
  for (int tp = 0; tp < NT; tp += 4) {
    body(tp + 0, 0, 1, 3, pA0, pA1, pB0, pB1);
    body(tp + 1, 1, 2, 0, pB0, pB1, pA0, pA1);
    body(tp + 2, 2, 3, 1, pA0, pA1, pB0, pB1);
    body(tp + 3, 3, 0, 2, pB0, pB1, pA0, pA1);
  }
#undef STAGE
#undef QKC

  // ---- epilogue: merge lane-half denominators, O^T[d][q]/lr -> ctx
  const float lrt = lr + __shfl_xor(lr, 32);
  const int b = bh >> 4, hh = bh & 15;
  unsigned short* crow = ctx + ((size_t)(b * Tt + q0w + lq)) * Dd + hh * DHc;
  const float inv = 1.f / lrt;
#pragma unroll
  for (int r = 0; r < 16; r += 2) {
    const int d = (r & 3) + 8 * (r >> 2) + 4 * h;
    const unsigned u0 = cvtpk(o0[r] * inv, o0[r + 1] * inv);
    const unsigned u1 = cvtpk(o1[r] * inv, o1[r + 1] * inv);
    *(unsigned*)(crow + d) = u0;
    *(unsigned*)(crow + 32 + d) = u1;
  }
}

// ---------------------------------------------------------------- launch
extern "C" void kernel_launch(void* const* d_in, const int* in_sizes, int n_in,
                              void* d_out, int out_size, void* d_ws, size_t ws_size,
                              hipStream_t stream) {
  (void)in_sizes; (void)n_in; (void)out_size; (void)ws_size;
  const float* x   = (const float*)d_in[0];
  const float* Wq  = (const float*)d_in[1];
  const float* bq  = (const float*)d_in[2];
  const float* Wk  = (const float*)d_in[3];
  const float* bk  = (const float*)d_in[4];
  const float* Wv  = (const float*)d_in[5];
  const float* bv  = (const float*)d_in[6];
  const float* Wo  = (const float*)d_in[7];
  const float* bo  = (const float*)d_in[8];
  const float* Wh  = (const float*)d_in[9];
  const float* bhi = (const float*)d_in[10];
  const float* Wy  = (const float*)d_in[11];
  const float* by  = (const float*)d_in[12];
  float* out = (float*)d_out;

  const size_t EL = (size_t)BT * Dd;  // 4M elements
  const size_t M1 = (size_t)Dd * Dd;  // 1M elements
  unsigned short* slotA = (unsigned short*)d_ws;  // 8MB : x16 -> ctx16 -> act16
  unsigned short* slotB = slotA + EL;             // 8MB : Q16 -> h16
  unsigned short* slotC = slotB + EL;             // 16MB: K16+Vt16
  unsigned short* wts   = slotC + 2 * EL;         // 12MB: [Wqkv^T 3M][Wo^T][Wh^T][Wy^T]
  unsigned short* WqkvT = wts;
  unsigned short* WoT   = wts + 3 * M1;
  unsigned short* WhT   = wts + 4 * M1;
  unsigned short* WyT   = wts + 5 * M1;

  unsigned short* x16   = slotA;
  unsigned short* Q16   = slotB;
  unsigned short* K16   = slotC;
  unsigned short* Vt16  = slotC + EL;
  unsigned short* ctx16 = slotA;            // x16 dead after QKV GEMM
  unsigned short* h16   = slotB;            // Q16 dead after attention
  unsigned short* act16 = slotA;            // ctx16 dead after Wo GEMM

  k_prep<<<dim3(32, 32, 7), dim3(32, 8), 0, stream>>>(x, Wq, Wk, Wv, Wo, Wh, Wy, wts, x16);

  k_gemm_qkv<<<dim3(768), 256, 0, stream>>>(x16, WqkvT, bq, bk, bv, Q16, K16, Vt16);

  k_attn<<<dim3(512), 256, 0, stream>>>(Q16, K16, Vt16, ctx16);

  k_gemm2<2><<<dim3(512), 256, 0, stream>>>(ctx16, WoT, bo, x, nullptr, nullptr, h16);
  k_gemm2<3><<<dim3(512), 256, 0, stream>>>(h16, WhT, bhi, nullptr, nullptr, nullptr, act16);
  k_gemm2<4><<<dim3(512), 256, 0, stream>>>(act16, WyT, by, nullptr, h16, out, nullptr);
}